// Round 1
// baseline (160.919 us; speedup 1.0000x reference)
//
#include <hip/hip_runtime.h>
#include <math.h>

namespace {
constexpr int BB   = 4;
constexpr int NCH  = 6;
constexpr int HH   = 512;
constexpr int WW   = 512;
constexpr int NCEN = 64;
constexpr int KSZ  = 21;
constexpr int PADR = 10;
constexpr float CEXT = 3.0f;
constexpr int HW   = HH * WW;

__global__ __launch_bounds__(256) void k_geom(
    const float* __restrict__ centers,   // [B][NCEN][2] (cy, cx)
    const float* __restrict__ gt,        // [B][6][H][W]
    float* __restrict__ out,             // [B][6][H][W]
    float* __restrict__ mask)            // [B][H][W]
{
    __shared__ float s_cy[NCEN], s_cx[NCEN];
    __shared__ int s_has;
    const int b   = blockIdx.y;
    const int tid = threadIdx.x;
    if (tid == 0) s_has = 0;
    __syncthreads();
    if (tid < NCEN) {
        float cy = centers[(b * NCEN + tid) * 2 + 0];
        float cx = centers[(b * NCEN + tid) * 2 + 1];
        bool valid = (cy > 0.0f) || (cx > 0.0f);
        if (valid) atomicOr(&s_has, 1);
        // invalid center: cy=+inf -> d2=+inf, matches where(valid, d2, inf)
        s_cy[tid] = valid ? cy : __int_as_float(0x7f800000);
        s_cx[tid] = cx;
    }
    __syncthreads();

    const int idx = blockIdx.x * 256 + tid;
    const int h = idx / WW, w = idx % WW;
    const float fh = (float)h, fw = (float)w;

    // argmin over centers; d2 values are exact integers in f32, strict <
    // keeps the first (lowest-index) minimum == jnp.argmin semantics.
    float best = __int_as_float(0x7f800000);
    int bi = 0;
#pragma unroll 8
    for (int i = 0; i < NCEN; ++i) {
        float dx = fh - s_cx[i];
        float dy = fw - s_cy[i];
        float d2 = dx * dx + dy * dy;
        if (d2 < best) { best = d2; bi = i; }
    }

    float gX = s_cx[bi] - fh;
    float gY = s_cy[bi] - fw;
    float r2 = gX * gX + gY * gY;
    bool rpos = r2 > 0.0f;
    float R  = rpos ? sqrtf(r2) : 0.0f;
    float th = atan2f(gY, rpos ? gX : 1.0f);
    float sn = sinf(th), cs = cosf(th);
    float M  = sqrtf(sn * sn + cs * cs);
    sn /= M; cs /= M;
    bool nearc = (fabsf(gX) < CEXT) && (fabsf(gY) < CEXT);
    bool hv = (s_has != 0);

    const size_t base = (size_t)b * NCH * HW + (size_t)idx;
    if (hv) {
        out[base + 0 * (size_t)HW] = R;
        out[base + 1 * (size_t)HW] = th;
        out[base + 2 * (size_t)HW] = sn;
        out[base + 3 * (size_t)HW] = cs;
    } else {
        out[base + 0 * (size_t)HW] = gt[base + 0 * (size_t)HW];
        out[base + 1 * (size_t)HW] = gt[base + 1 * (size_t)HW];
        out[base + 2 * (size_t)HW] = gt[base + 2 * (size_t)HW];
        out[base + 3 * (size_t)HW] = gt[base + 3 * (size_t)HW];
    }
    out[base + 4 * (size_t)HW] = gt[base + 4 * (size_t)HW];
    mask[(size_t)b * HW + idx] = (hv && nearc) ? 1.0f : 0.0f;
}

__device__ __forceinline__ void load_k1(const float* __restrict__ g2d, float* k1) {
    // 1D kernel = row sums of the normalized 2D kernel (exact: e_i/s).
    if (threadIdx.x < KSZ) {
        float s = 0.0f;
#pragma unroll
        for (int j = 0; j < KSZ; ++j) s += g2d[threadIdx.x * KSZ + j];
        k1[threadIdx.x] = s;
    }
    __syncthreads();
}

__device__ __forceinline__ int refl(int q, int n) {
    q = (q < 0) ? -q : q;
    q = (q >= n) ? (2 * n - 2 - q) : q;
    return q;
}

__global__ __launch_bounds__(256) void k_blur_v(
    const float* __restrict__ mask,
    const float* __restrict__ g2d,
    float* __restrict__ out)            // writes ch5 as tmp
{
    __shared__ float k1[KSZ];
    load_k1(g2d, k1);
    const int b = blockIdx.y;
    const int idx = blockIdx.x * 256 + threadIdx.x;
    const int h = idx / WW, w = idx % WW;
    const float* mb = mask + (size_t)b * HW;
    float acc = 0.0f;
#pragma unroll
    for (int d = -PADR; d <= PADR; ++d) {
        int q = refl(h + d, HH);
        acc = fmaf(k1[d + PADR], mb[q * WW + w], acc);
    }
    out[((size_t)b * NCH + 5) * HW + idx] = acc;
}

__global__ __launch_bounds__(256) void k_blur_h(
    const float* __restrict__ outin,    // reads ch5 tmp
    const float* __restrict__ g2d,
    float* __restrict__ blurred,        // ws (reuses mask buffer)
    unsigned int* __restrict__ maxbuf)
{
    __shared__ float k1[KSZ];
    load_k1(g2d, k1);
    const int b = blockIdx.y;
    const int idx = blockIdx.x * 256 + threadIdx.x;
    const int h = idx / WW, w = idx % WW;
    const float* tb = outin + ((size_t)b * NCH + 5) * HW + (size_t)h * WW;
    float acc = 0.0f;
#pragma unroll
    for (int d = -PADR; d <= PADR; ++d) {
        int q = refl(w + d, WW);
        acc = fmaf(k1[d + PADR], tb[q], acc);
    }
    blurred[(size_t)b * HW + idx] = acc;

    // block max -> one atomic per block (nonneg floats: uint order == float order)
    float v = acc;
#pragma unroll
    for (int off = 32; off > 0; off >>= 1)
        v = fmaxf(v, __shfl_down(v, off, 64));
    __shared__ float swr[4];
    const int lane = threadIdx.x & 63, wid = threadIdx.x >> 6;
    if (lane == 0) swr[wid] = v;
    __syncthreads();
    if (threadIdx.x == 0) {
        float m = fmaxf(fmaxf(swr[0], swr[1]), fmaxf(swr[2], swr[3]));
        atomicMax(&maxbuf[b], __float_as_uint(m));
    }
}

__global__ __launch_bounds__(256) void k_norm(
    const float* __restrict__ blurred,
    const unsigned int* __restrict__ maxbuf,
    float* __restrict__ out)
{
    const int b = blockIdx.y;
    const int idx = blockIdx.x * 256 + threadIdx.x;
    float m = __uint_as_float(maxbuf[b]);
    // unconditional: if mask was empty, blurred==0 -> 0/1e-12 == 0 == reference
    out[((size_t)b * NCH + 5) * HW + idx] = blurred[(size_t)b * HW + idx] / fmaxf(m, 1e-12f);
}

} // namespace

extern "C" void kernel_launch(void* const* d_in, const int* in_sizes, int n_in,
                              void* d_out, int out_size, void* d_ws, size_t ws_size,
                              hipStream_t stream) {
    (void)in_sizes; (void)n_in; (void)out_size; (void)ws_size;
    const float* centers = (const float*)d_in[0];
    const float* gt      = (const float*)d_in[1];
    const float* g2d     = (const float*)d_in[2];
    float* out  = (float*)d_out;
    float* mask = (float*)d_ws;
    unsigned int* maxbuf = (unsigned int*)((char*)d_ws + (size_t)BB * HW * sizeof(float));

    hipMemsetAsync(maxbuf, 0, BB * sizeof(unsigned int), stream);
    dim3 grid(HW / 256, BB);
    k_geom  <<<grid, 256, 0, stream>>>(centers, gt, out, mask);
    k_blur_v<<<grid, 256, 0, stream>>>(mask, g2d, out);
    k_blur_h<<<grid, 256, 0, stream>>>(out, g2d, mask, maxbuf);
    k_norm  <<<grid, 256, 0, stream>>>(mask, maxbuf, out);
}

// Round 3
// 110.335 us; speedup vs baseline: 1.4585x; 1.4585x over previous
//
#include <hip/hip_runtime.h>
#include <math.h>
#include <limits.h>

namespace {
constexpr int BB   = 4;
constexpr int NCH  = 6;
constexpr int HH   = 512;
constexpr int WW   = 512;
constexpr int NCEN = 64;
constexpr int KSZ  = 21;
constexpr int PADR = 10;
constexpr int HW   = HH * WW;
constexpr int SENT = -1024;          // invalid-center sentinel coordinate

__device__ __forceinline__ int refl(int q, int n) {
    q = (q < 0) ? -q : q;
    q = (q >= n) ? (2 * n - 2 - q) : q;
    return q;
}

// ---------------------------------------------------------------------------
// Dense kernel: ch0-3 geometry (or gt copy), ch4 copy, ch5 = 0, mask write.
// 4 pixels/thread, block = 256 threads = 2 rows of 512.
// Argmin key: p_i = 64*d2 + i, exact integers (d2 <= 2*1535^2, *64 < 2^31),
// strict-min keeps lowest index on ties == jnp.argmin.
// ---------------------------------------------------------------------------
__global__ __launch_bounds__(256) void k_geom(
    const float* __restrict__ centers,   // [B][NCEN][2] (cy, cx)
    const float* __restrict__ gt,        // [B][6][H][W]
    float* __restrict__ out,             // [B][6][H][W]
    float* __restrict__ mask)            // [B][H][W]
{
    __shared__ int2  s_cen[2][NCEN];     // {icy*8, 64*(row-icx)^2 + i} per row
    __shared__ float s_cxf[NCEN], s_cyf[NCEN];
    __shared__ int   s_has;

    const int b   = blockIdx.y;
    const int tid = threadIdx.x;
    const int r0  = blockIdx.x * 2;

    if (tid == 0) s_has = 0;
    __syncthreads();
    if (tid < NCEN) {
        float cy = centers[(b * NCEN + tid) * 2 + 0];
        float cx = centers[(b * NCEN + tid) * 2 + 1];
        bool valid = (cy > 0.0f) || (cx > 0.0f);
        if (valid) atomicOr(&s_has, 1);
        s_cyf[tid] = cy;
        s_cxf[tid] = cx;
        int icx = valid ? (int)cx : SENT;
        int icy = valid ? (int)cy : SENT;
        int dx0 = r0 - icx;
        int dx1 = r0 + 1 - icx;
        s_cen[0][tid] = make_int2(icy * 8, 64 * dx0 * dx0 + tid);
        s_cen[1][tid] = make_int2(icy * 8, 64 * dx1 * dx1 + tid);
    }
    __syncthreads();

    const int rr  = tid >> 7;            // 0/1: which row (wave-uniform)
    const int w0  = (tid & 127) * 4;     // 4 consecutive pixels
    const int row = r0 + rr;
    const int idx0 = row * WW + w0;

    const int iw8_0 = (w0 + 0) * 8;
    const int iw8_1 = (w0 + 1) * 8;
    const int iw8_2 = (w0 + 2) * 8;
    const int iw8_3 = (w0 + 3) * 8;
    int b0 = INT_MAX, b1 = INT_MAX, b2 = INT_MAX, b3 = INT_MAX;

    const int2* cen = s_cen[rr];
#pragma unroll 8
    for (int i = 0; i < NCEN; ++i) {
        int2 c = cen[i];
        int d0 = iw8_0 - c.x; b0 = min(b0, __mul24(d0, d0) + c.y);
        int d1 = iw8_1 - c.x; b1 = min(b1, __mul24(d1, d1) + c.y);
        int d2 = iw8_2 - c.x; b2 = min(b2, __mul24(d2, d2) + c.y);
        int d3 = iw8_3 - c.x; b3 = min(b3, __mul24(d3, d3) + c.y);
    }
    int bi[4] = { b0 & 63, b1 & 63, b2 & 63, b3 & 63 };

    const bool hv = (s_has != 0);
    float aR[4], aT[4], aS[4], aC[4], aM[4];
    const float fh = (float)row;
#pragma unroll
    for (int j = 0; j < 4; ++j) {
        float cxw = s_cxf[bi[j]];
        float cyw = s_cyf[bi[j]];
        float gX = cxw - fh;
        float gY = cyw - (float)(w0 + j);
        float r2 = gX * gX + gY * gY;      // exact small integers
        bool rpos = r2 > 0.0f;
        float R = rpos ? sqrtf(r2) : 0.0f;
        aR[j] = R;
        aT[j] = atan2f(gY, rpos ? gX : 1.0f);
        float invR = rpos ? (1.0f / R) : 0.0f;
        aS[j] = rpos ? gY * invR : 0.0f;   // sin(atan2(gY,gX)) == gY/R
        aC[j] = rpos ? gX * invR : 1.0f;   // cos(atan2(gY,gX)) == gX/R
        bool nearc = (fabsf(gX) < 3.0f) && (fabsf(gY) < 3.0f);
        aM[j] = (hv && nearc) ? 1.0f : 0.0f;
    }

    const size_t base = (size_t)b * NCH * HW + (size_t)idx0;
    if (hv) {
        *(float4*)&out[base + 0 * (size_t)HW] = make_float4(aR[0], aR[1], aR[2], aR[3]);
        *(float4*)&out[base + 1 * (size_t)HW] = make_float4(aT[0], aT[1], aT[2], aT[3]);
        *(float4*)&out[base + 2 * (size_t)HW] = make_float4(aS[0], aS[1], aS[2], aS[3]);
        *(float4*)&out[base + 3 * (size_t)HW] = make_float4(aC[0], aC[1], aC[2], aC[3]);
    } else {
        *(float4*)&out[base + 0 * (size_t)HW] = *(const float4*)&gt[base + 0 * (size_t)HW];
        *(float4*)&out[base + 1 * (size_t)HW] = *(const float4*)&gt[base + 1 * (size_t)HW];
        *(float4*)&out[base + 2 * (size_t)HW] = *(const float4*)&gt[base + 2 * (size_t)HW];
        *(float4*)&out[base + 3 * (size_t)HW] = *(const float4*)&gt[base + 3 * (size_t)HW];
    }
    *(float4*)&out[base + 4 * (size_t)HW] = *(const float4*)&gt[base + 4 * (size_t)HW];
    *(float4*)&out[base + 5 * (size_t)HW] = make_float4(0.f, 0.f, 0.f, 0.f);
    *(float4*)&mask[(size_t)b * HW + idx0] = make_float4(aM[0], aM[1], aM[2], aM[3]);
}

// ---------------------------------------------------------------------------
// Sparse blur over box(center, 12): separable, reflect per-axis.
// tmp rows = output rows (<=25), tmp cols = [cLo,cHi] (<=45).
// ---------------------------------------------------------------------------
__device__ __forceinline__ void load_k1(const float* __restrict__ g2d, float* k1) {
    if (threadIdx.x < KSZ) {
        float s = 0.0f;
#pragma unroll
        for (int j = 0; j < KSZ; ++j) s += g2d[threadIdx.x * KSZ + j];
        k1[threadIdx.x] = s;
    }
}

__device__ __forceinline__ void vpass(const float* __restrict__ mb,
                                      const float* __restrict__ k1,
                                      float* __restrict__ tmp,
                                      int rA, int nh, int cLo, int nwT) {
    for (int e = threadIdx.x; e < nh * nwT; e += 256) {
        int lr = e / nwT;
        int c  = cLo + (e - lr * nwT);
        int r  = rA + lr;
        float acc = 0.0f;
#pragma unroll
        for (int dv = -PADR; dv <= PADR; ++dv) {
            int q = refl(r + dv, HH);
            acc = fmaf(k1[dv + PADR], mb[q * WW + c], acc);
        }
        tmp[lr * 46 + (c - cLo)] = acc;
    }
}

__global__ __launch_bounds__(256) void k_blur_sparse(
    const float* __restrict__ centers,
    const float* __restrict__ mask,
    const float* __restrict__ g2d,
    unsigned int* __restrict__ maxbuf)
{
    const int b  = blockIdx.y;
    const int ci = blockIdx.x;
    float cy = centers[(b * NCEN + ci) * 2 + 0];
    float cx = centers[(b * NCEN + ci) * 2 + 1];
    if (!((cy > 0.0f) || (cx > 0.0f))) return;     // uniform exit, no barriers yet
    int icx = (int)cx, icy = (int)cy;
    int rA = max(icx - 12, 0), rB = min(icx + 12, HH - 1);
    int cA = max(icy - 12, 0), cB = min(icy + 12, WW - 1);
    int cLo = max(cA - PADR, 0), cHi = min(cB + PADR, WW - 1);
    int nh = rB - rA + 1, nw = cB - cA + 1, nwT = cHi - cLo + 1;

    __shared__ float k1[KSZ];
    __shared__ float tmp[25 * 46];
    load_k1(g2d, k1);
    __syncthreads();
    vpass(mask + (size_t)b * HW, k1, tmp, rA, nh, cLo, nwT);
    __syncthreads();

    float vmax = 0.0f;
    for (int e = threadIdx.x; e < nh * nw; e += 256) {
        int lr = e / nw;
        int w  = cA + (e - lr * nw);
        float acc = 0.0f;
#pragma unroll
        for (int d = -PADR; d <= PADR; ++d) {
            int q = refl(w + d, WW);
            acc = fmaf(k1[d + PADR], tmp[lr * 46 + (q - cLo)], acc);
        }
        vmax = fmaxf(vmax, acc);
    }
#pragma unroll
    for (int off = 32; off > 0; off >>= 1)
        vmax = fmaxf(vmax, __shfl_down(vmax, off, 64));
    __shared__ float swr[4];
    const int lane = threadIdx.x & 63, wid = threadIdx.x >> 6;
    if (lane == 0) swr[wid] = vmax;
    __syncthreads();
    if (threadIdx.x == 0) {
        float m = fmaxf(fmaxf(swr[0], swr[1]), fmaxf(swr[2], swr[3]));
        atomicMax(&maxbuf[b], __float_as_uint(m));   // nonneg: uint order == float order
    }
}

__global__ __launch_bounds__(256) void k_norm_sparse(
    const float* __restrict__ centers,
    const float* __restrict__ mask,
    const float* __restrict__ g2d,
    const unsigned int* __restrict__ maxbuf,
    float* __restrict__ out)
{
    const int b  = blockIdx.y;
    const int ci = blockIdx.x;
    float cy = centers[(b * NCEN + ci) * 2 + 0];
    float cx = centers[(b * NCEN + ci) * 2 + 1];
    if (!((cy > 0.0f) || (cx > 0.0f))) return;
    int icx = (int)cx, icy = (int)cy;
    int rA = max(icx - 12, 0), rB = min(icx + 12, HH - 1);
    int cA = max(icy - 12, 0), cB = min(icy + 12, WW - 1);
    int cLo = max(cA - PADR, 0), cHi = min(cB + PADR, WW - 1);
    int nh = rB - rA + 1, nw = cB - cA + 1, nwT = cHi - cLo + 1;

    __shared__ float k1[KSZ];
    __shared__ float tmp[25 * 46];
    load_k1(g2d, k1);
    __syncthreads();
    vpass(mask + (size_t)b * HW, k1, tmp, rA, nh, cLo, nwT);
    __syncthreads();

    const float inv = 1.0f / fmaxf(__uint_as_float(maxbuf[b]), 1e-12f);
    float* o5 = out + ((size_t)b * NCH + 5) * HW;
    for (int e = threadIdx.x; e < nh * nw; e += 256) {
        int lr = e / nw;
        int w  = cA + (e - lr * nw);
        float acc = 0.0f;
#pragma unroll
        for (int d = -PADR; d <= PADR; ++d) {
            int q = refl(w + d, WW);
            acc = fmaf(k1[d + PADR], tmp[lr * 46 + (q - cLo)], acc);
        }
        o5[(rA + lr) * WW + w] = acc * inv;   // overwrites k_geom's zero
    }
}

} // namespace

extern "C" void kernel_launch(void* const* d_in, const int* in_sizes, int n_in,
                              void* d_out, int out_size, void* d_ws, size_t ws_size,
                              hipStream_t stream) {
    (void)in_sizes; (void)n_in; (void)out_size; (void)ws_size;
    const float* centers = (const float*)d_in[0];
    const float* gt      = (const float*)d_in[1];
    const float* g2d     = (const float*)d_in[2];
    float* out  = (float*)d_out;
    float* mask = (float*)d_ws;
    unsigned int* maxbuf = (unsigned int*)((char*)d_ws + (size_t)BB * HW * sizeof(float));

    hipMemsetAsync(maxbuf, 0, BB * sizeof(unsigned int), stream);
    dim3 gridG(HW / 1024, BB);                 // 256 blocks/batch, 2 rows each
    k_geom<<<gridG, 256, 0, stream>>>(centers, gt, out, mask);
    dim3 gridS(NCEN, BB);
    k_blur_sparse<<<gridS, 256, 0, stream>>>(centers, mask, g2d, maxbuf);
    k_norm_sparse<<<gridS, 256, 0, stream>>>(centers, mask, g2d, maxbuf, out);
}

// Round 6
// 99.001 us; speedup vs baseline: 1.6254x; 1.1145x over previous
//
#include <hip/hip_runtime.h>
#include <math.h>
#include <limits.h>

namespace {
constexpr int BB   = 4;
constexpr int NCH  = 6;
constexpr int HH   = 512;
constexpr int WW   = 512;
constexpr int NCEN = 64;
constexpr int KSZ  = 21;
constexpr int PADR = 10;
constexpr int HW   = HH * WW;
constexpr int SENT = -1024;          // invalid-center sentinel coordinate
constexpr int BOXSTRIDE = 640;       // per-(b,ci) blurbox slot (25*25 rounded up)

__device__ __forceinline__ int refl(int q, int n) {
    q = (q < 0) ? -q : q;
    q = (q >= n) ? (2 * n - 2 - q) : q;
    return q;
}

// ---------------------------------------------------------------------------
// Dense kernel: ch0-3 geometry (or gt copy), ch4 copy, ch5 = 0, mask write,
// maxbuf zero (replaces a memset dispatch; stream order guarantees it lands
// before k_blur_sparse's atomics).
// 4 pixels/thread, block = 256 threads = 2 rows of 512.
// Argmin key: p_i = 64*d2 + i, exact integers (d2 <= 2*1535^2, *64 < 2^31),
// strict-min keeps lowest index on ties == jnp.argmin.
// ---------------------------------------------------------------------------
__global__ __launch_bounds__(256) void k_geom(
    const float* __restrict__ centers,   // [B][NCEN][2] (cy, cx)
    const float* __restrict__ gt,        // [B][6][H][W]
    float* __restrict__ out,             // [B][6][H][W]
    float* __restrict__ mask,            // [B][H][W]
    unsigned int* __restrict__ maxbuf)   // [B]
{
    __shared__ int2  s_cen[2][NCEN];     // {icy*8, 64*(row-icx)^2 + i} per row
    __shared__ float s_cxf[NCEN], s_cyf[NCEN];
    __shared__ int   s_has;

    const int b   = blockIdx.y;
    const int tid = threadIdx.x;
    const int r0  = blockIdx.x * 2;

    if (blockIdx.x == 0 && tid == 0) maxbuf[b] = 0u;   // ws is 0xAA-poisoned
    if (tid == 0) s_has = 0;
    __syncthreads();
    if (tid < NCEN) {
        float cy = centers[(b * NCEN + tid) * 2 + 0];
        float cx = centers[(b * NCEN + tid) * 2 + 1];
        bool valid = (cy > 0.0f) || (cx > 0.0f);
        if (valid) atomicOr(&s_has, 1);
        s_cyf[tid] = cy;
        s_cxf[tid] = cx;
        int icx = valid ? (int)cx : SENT;
        int icy = valid ? (int)cy : SENT;
        int dx0 = r0 - icx;
        int dx1 = r0 + 1 - icx;
        s_cen[0][tid] = make_int2(icy * 8, 64 * dx0 * dx0 + tid);
        s_cen[1][tid] = make_int2(icy * 8, 64 * dx1 * dx1 + tid);
    }
    __syncthreads();

    const int rr  = tid >> 7;            // 0/1: which row (wave-uniform)
    const int w0  = (tid & 127) * 4;     // 4 consecutive pixels
    const int row = r0 + rr;
    const int idx0 = row * WW + w0;

    const int iw8_0 = (w0 + 0) * 8;
    const int iw8_1 = (w0 + 1) * 8;
    const int iw8_2 = (w0 + 2) * 8;
    const int iw8_3 = (w0 + 3) * 8;
    int b0 = INT_MAX, b1 = INT_MAX, b2 = INT_MAX, b3 = INT_MAX;

    const int2* cen = s_cen[rr];
#pragma unroll 8
    for (int i = 0; i < NCEN; ++i) {
        int2 c = cen[i];
        int d0 = iw8_0 - c.x; b0 = min(b0, __mul24(d0, d0) + c.y);
        int d1 = iw8_1 - c.x; b1 = min(b1, __mul24(d1, d1) + c.y);
        int d2 = iw8_2 - c.x; b2 = min(b2, __mul24(d2, d2) + c.y);
        int d3 = iw8_3 - c.x; b3 = min(b3, __mul24(d3, d3) + c.y);
    }
    int bi[4] = { b0 & 63, b1 & 63, b2 & 63, b3 & 63 };

    const bool hv = (s_has != 0);
    float aR[4], aT[4], aS[4], aC[4], aM[4];
    const float fh = (float)row;
#pragma unroll
    for (int j = 0; j < 4; ++j) {
        float cxw = s_cxf[bi[j]];
        float cyw = s_cyf[bi[j]];
        float gX = cxw - fh;
        float gY = cyw - (float)(w0 + j);
        float r2 = gX * gX + gY * gY;      // exact small integers
        bool rpos = r2 > 0.0f;
        float R = rpos ? sqrtf(r2) : 0.0f;
        aR[j] = R;
        aT[j] = atan2f(gY, rpos ? gX : 1.0f);
        float invR = rpos ? (1.0f / R) : 0.0f;
        aS[j] = rpos ? gY * invR : 0.0f;   // sin(atan2(gY,gX)) == gY/R
        aC[j] = rpos ? gX * invR : 1.0f;   // cos(atan2(gY,gX)) == gX/R
        bool nearc = (fabsf(gX) < 3.0f) && (fabsf(gY) < 3.0f);
        aM[j] = (hv && nearc) ? 1.0f : 0.0f;
    }

    const size_t base = (size_t)b * NCH * HW + (size_t)idx0;
    if (hv) {
        *(float4*)&out[base + 0 * (size_t)HW] = make_float4(aR[0], aR[1], aR[2], aR[3]);
        *(float4*)&out[base + 1 * (size_t)HW] = make_float4(aT[0], aT[1], aT[2], aT[3]);
        *(float4*)&out[base + 2 * (size_t)HW] = make_float4(aS[0], aS[1], aS[2], aS[3]);
        *(float4*)&out[base + 3 * (size_t)HW] = make_float4(aC[0], aC[1], aC[2], aC[3]);
    } else {
        *(float4*)&out[base + 0 * (size_t)HW] = *(const float4*)&gt[base + 0 * (size_t)HW];
        *(float4*)&out[base + 1 * (size_t)HW] = *(const float4*)&gt[base + 1 * (size_t)HW];
        *(float4*)&out[base + 2 * (size_t)HW] = *(const float4*)&gt[base + 2 * (size_t)HW];
        *(float4*)&out[base + 3 * (size_t)HW] = *(const float4*)&gt[base + 3 * (size_t)HW];
    }
    *(float4*)&out[base + 4 * (size_t)HW] = *(const float4*)&gt[base + 4 * (size_t)HW];
    *(float4*)&out[base + 5 * (size_t)HW] = make_float4(0.f, 0.f, 0.f, 0.f);
    *(float4*)&mask[(size_t)b * HW + idx0] = make_float4(aM[0], aM[1], aM[2], aM[3]);
}

// ---------------------------------------------------------------------------
// Sparse blur over box(center, 12): mask patch staged in LDS, separable blur
// from LDS, box result stored to ws (blurbox) + per-batch atomicMax.
// Arithmetic order per output pixel is independent of which block computes it
// -> overlapping boxes produce bit-identical values.
// ---------------------------------------------------------------------------
__device__ __forceinline__ void load_k1(const float* __restrict__ g2d, float* k1) {
    if (threadIdx.x < KSZ) {
        float s = 0.0f;
#pragma unroll
        for (int j = 0; j < KSZ; ++j) s += g2d[threadIdx.x * KSZ + j];
        k1[threadIdx.x] = s;
    }
}

__global__ __launch_bounds__(256) void k_blur_sparse(
    const float* __restrict__ centers,
    const float* __restrict__ mask,
    const float* __restrict__ g2d,
    float* __restrict__ blurbox,
    unsigned int* __restrict__ maxbuf)
{
    const int b  = blockIdx.y;
    const int ci = blockIdx.x;
    float cy = centers[(b * NCEN + ci) * 2 + 0];
    float cx = centers[(b * NCEN + ci) * 2 + 1];
    if (!((cy > 0.0f) || (cx > 0.0f))) return;     // uniform exit before barriers
    const int icx = (int)cx, icy = (int)cy;
    const int rA = max(icx - 12, 0), rB = min(icx + 12, HH - 1);
    const int cA = max(icy - 12, 0), cB = min(icy + 12, WW - 1);
    const int pr0 = max(rA - PADR, 0), pr1 = min(rB + PADR, HH - 1);
    const int pc0 = max(cA - PADR, 0), pc1 = min(cB + PADR, WW - 1);
    const int nr = pr1 - pr0 + 1, nc = pc1 - pc0 + 1;   // <= 45
    const int nh = rB - rA + 1,  nw = cB - cA + 1;      // <= 25

    __shared__ float k1[KSZ];
    __shared__ float patch[45 * 48];
    __shared__ float tmp[25 * 46];
    load_k1(g2d, k1);

    const float* mb = mask + (size_t)b * HW;
    for (int e = threadIdx.x; e < nr * nc; e += 256) {
        int r = e / nc, c = e - r * nc;
        patch[r * 48 + c] = mb[(pr0 + r) * WW + (pc0 + c)];
    }
    __syncthreads();

    // vertical pass: tmp[lr][j] over all patch columns
    for (int e = threadIdx.x; e < nh * nc; e += 256) {
        int lr = e / nc, j = e - lr * nc;
        int r  = rA + lr;
        float acc = 0.0f;
#pragma unroll
        for (int dv = -PADR; dv <= PADR; ++dv) {
            int q = refl(r + dv, HH);
            acc = fmaf(k1[dv + PADR], patch[(q - pr0) * 48 + j], acc);
        }
        tmp[lr * 46 + j] = acc;
    }
    __syncthreads();

    // horizontal pass + store + max
    float vmax = 0.0f;
    float* bx = blurbox + (size_t)(b * NCEN + ci) * BOXSTRIDE;
    for (int e = threadIdx.x; e < nh * nw; e += 256) {
        int lr = e / nw, j = e - lr * nw;
        int w  = cA + j;
        float acc = 0.0f;
#pragma unroll
        for (int d = -PADR; d <= PADR; ++d) {
            int q = refl(w + d, WW);
            acc = fmaf(k1[d + PADR], tmp[lr * 46 + (q - pc0)], acc);
        }
        bx[lr * 25 + j] = acc;
        vmax = fmaxf(vmax, acc);
    }
#pragma unroll
    for (int off = 32; off > 0; off >>= 1)
        vmax = fmaxf(vmax, __shfl_down(vmax, off, 64));
    __shared__ float swr[4];
    const int lane = threadIdx.x & 63, wid = threadIdx.x >> 6;
    if (lane == 0) swr[wid] = vmax;
    __syncthreads();
    if (threadIdx.x == 0) {
        float m = fmaxf(fmaxf(swr[0], swr[1]), fmaxf(swr[2], swr[3]));
        atomicMax(&maxbuf[b], __float_as_uint(m));   // nonneg: uint order == float order
    }
}

__global__ __launch_bounds__(256) void k_norm_sparse(
    const float* __restrict__ centers,
    const float* __restrict__ blurbox,
    const unsigned int* __restrict__ maxbuf,
    float* __restrict__ out)
{
    const int b  = blockIdx.y;
    const int ci = blockIdx.x;
    float cy = centers[(b * NCEN + ci) * 2 + 0];
    float cx = centers[(b * NCEN + ci) * 2 + 1];
    if (!((cy > 0.0f) || (cx > 0.0f))) return;
    const int icx = (int)cx, icy = (int)cy;
    const int rA = max(icx - 12, 0), rB = min(icx + 12, HH - 1);
    const int cA = max(icy - 12, 0), cB = min(icy + 12, WW - 1);
    const int nh = rB - rA + 1, nw = cB - cA + 1;

    const float inv = 1.0f / fmaxf(__uint_as_float(maxbuf[b]), 1e-12f);
    const float* bx = blurbox + (size_t)(b * NCEN + ci) * BOXSTRIDE;
    float* o5 = out + ((size_t)b * NCH + 5) * HW;
    for (int e = threadIdx.x; e < nh * nw; e += 256) {
        int lr = e / nw, j = e - lr * nw;
        o5[(rA + lr) * WW + (cA + j)] = bx[lr * 25 + j] * inv;  // overwrites k_geom's zero
    }
}

} // namespace

extern "C" void kernel_launch(void* const* d_in, const int* in_sizes, int n_in,
                              void* d_out, int out_size, void* d_ws, size_t ws_size,
                              hipStream_t stream) {
    (void)in_sizes; (void)n_in; (void)out_size; (void)ws_size;
    const float* centers = (const float*)d_in[0];
    const float* gt      = (const float*)d_in[1];
    const float* g2d     = (const float*)d_in[2];
    float* out  = (float*)d_out;
    float* mask = (float*)d_ws;                                   // BB*HW floats
    float* blurbox = (float*)d_ws + (size_t)BB * HW;              // BB*NCEN*640 floats
    unsigned int* maxbuf =
        (unsigned int*)((float*)d_ws + (size_t)BB * HW + (size_t)BB * NCEN * BOXSTRIDE);

    dim3 gridG(HW / 1024, BB);                 // 256 blocks/batch, 2 rows each
    k_geom<<<gridG, 256, 0, stream>>>(centers, gt, out, mask, maxbuf);
    dim3 gridS(NCEN, BB);
    k_blur_sparse<<<gridS, 256, 0, stream>>>(centers, mask, g2d, blurbox, maxbuf);
    k_norm_sparse<<<gridS, 256, 0, stream>>>(centers, blurbox, maxbuf, out);
}

// Round 7
// 94.844 us; speedup vs baseline: 1.6967x; 1.0438x over previous
//
#include <hip/hip_runtime.h>
#include <math.h>
#include <limits.h>

namespace {
constexpr int BB   = 4;
constexpr int NCH  = 6;
constexpr int HH   = 512;
constexpr int WW   = 512;
constexpr int NCEN = 64;
constexpr int KSZ  = 21;
constexpr int PADR = 10;
constexpr int HW   = HH * WW;
constexpr int BOXSTRIDE = 640;       // per-(b,ci) blurbox slot (25*25 rounded up)

__device__ __forceinline__ int refl(int q, int n) {
    q = (q < 0) ? -q : q;
    q = (q >= n) ? (2 * n - 2 - q) : q;
    return q;
}

// Minimax atan2, abs err ~1e-5 rad (vs atan2f's ~60-100 instr).
// Callers guarantee not both args zero.
__device__ __forceinline__ float fast_atan2(float y, float x) {
    float ax = fabsf(x), ay = fabsf(y);
    float mx = fmaxf(ax, ay), mn = fminf(ax, ay);
    float r = mn / mx;                 // [0,1]
    float s = r * r;
    float p = -0.0117212f;
    p = fmaf(p, s, 0.05265332f);
    p = fmaf(p, s, -0.11643287f);
    p = fmaf(p, s, 0.19354346f);
    p = fmaf(p, s, -0.33262347f);
    p = fmaf(p, s, 0.99997726f);
    float a = r * p;                   // atan(mn/mx)
    a = (ay > ax) ? 1.57079632679489662f - a : a;
    a = (x < 0.0f) ? 3.14159265358979323f - a : a;
    return (y < 0.0f) ? -a : a;
}

// ---------------------------------------------------------------------------
// Dense kernel, 32x32 tiles, 4 px/thread. Tile-pruned argmin:
//   ub = min_i maxdist2(c_i, tile);  keep i iff mindist2(c_i, tile) <= ub.
// Conservative proof: pruned i has d2(p) >= mindist2_i > ub >= d_win(p) for
// every tile pixel p (strict), so winners AND ties survive pruning.
// Packed key 64*d2 + i (exact ints < 2^31) keeps jnp.argmin tie-break.
// ---------------------------------------------------------------------------
__global__ __launch_bounds__(256) void k_geom(
    const float* __restrict__ centers,   // [B][NCEN][2] (cy, cx)
    const float* __restrict__ gt,        // [B][6][H][W]
    float* __restrict__ out,             // [B][6][H][W]
    float* __restrict__ mask,            // [B][H][W]
    unsigned int* __restrict__ maxbuf)   // [B]
{
    __shared__ float s_cxf[NCEN], s_cyf[NCEN];
    __shared__ int   s_kx[NCEN], s_ky8[NCEN], s_ki[NCEN];
    __shared__ int   s_cnt, s_hasv;

    const int b    = blockIdx.y;
    const int tid  = threadIdx.x;
    const int tIdx = blockIdx.x;          // 0..255
    const int r0   = (tIdx >> 4) * 32;    // tile row base (h)
    const int c0   = (tIdx & 15) * 32;    // tile col base (w)

    if (tIdx == 0 && tid == 0) maxbuf[b] = 0u;   // ws is 0xAA-poisoned

    if (tid < NCEN) {                     // wave 0 only: prune + compact
        float cy = centers[(b * NCEN + tid) * 2 + 0];
        float cx = centers[(b * NCEN + tid) * 2 + 1];
        bool valid = (cy > 0.0f) || (cx > 0.0f);
        s_cxf[tid] = cx;
        s_cyf[tid] = cy;
        // rows pair with cx, cols with cy (dx = h - cx, dy = w - cy)
        float r0f = (float)r0, r1f = (float)(r0 + 31);
        float c0f = (float)c0, c1f = (float)(c0 + 31);
        float drm = fmaxf(fmaxf(r0f - cx, cx - r1f), 0.0f);
        float dcm = fmaxf(fmaxf(c0f - cy, cy - c1f), 0.0f);
        float drM = fmaxf(cx - r0f, r1f - cx);
        float dcM = fmaxf(cy - c0f, c1f - cy);
        float mind2 = drm * drm + dcm * dcm;   // exact ints in f32
        float maxd2 = drM * drM + dcM * dcM;
        if (!valid) { mind2 = __int_as_float(0x7f800000); maxd2 = mind2; }
        float ub = maxd2;
#pragma unroll
        for (int off = 32; off > 0; off >>= 1)
            ub = fminf(ub, __shfl_xor(ub, off, 64));
        bool keep = valid && (mind2 <= ub);
        unsigned long long km = __ballot(keep);
        unsigned long long vm = __ballot(valid);
        if (keep) {
            int pos = __popcll(km & ((1ull << tid) - 1ull));
            s_kx[pos]  = (int)cx;
            s_ky8[pos] = ((int)cy) * 8;
            s_ki[pos]  = tid;              // ascending original index order
        }
        if (tid == 0) { s_cnt = (int)__popcll(km); s_hasv = (vm != 0ull) ? 1 : 0; }
    }
    __syncthreads();

    const int row = r0 + (tid >> 3);       // 32 rows, 8 threads/row
    const int wb  = c0 + (tid & 7) * 4;    // 4 consecutive pixels
    const int w8  = wb * 8;
    const int cnt = s_cnt;
    const bool hv = (s_hasv != 0);

    int b0 = INT_MAX, b1 = INT_MAX, b2 = INT_MAX, b3 = INT_MAX;
    for (int k = 0; k < cnt; ++k) {
        int dr   = row - s_kx[k];
        int base = (__mul24(dr, dr) << 6) + s_ki[k];   // 64*dr^2 + i
        int icy8 = s_ky8[k];
        int d0 = w8      - icy8; b0 = min(b0, __mul24(d0, d0) + base);
        int d1 = w8 + 8  - icy8; b1 = min(b1, __mul24(d1, d1) + base);
        int d2 = w8 + 16 - icy8; b2 = min(b2, __mul24(d2, d2) + base);
        int d3 = w8 + 24 - icy8; b3 = min(b3, __mul24(d3, d3) + base);
    }
    int bi[4] = { b0 & 63, b1 & 63, b2 & 63, b3 & 63 };

    float aR[4], aT[4], aS[4], aC[4], aM[4];
    const float fh = (float)row;
#pragma unroll
    for (int j = 0; j < 4; ++j) {
        float cxw = s_cxf[bi[j]];
        float cyw = s_cyf[bi[j]];
        float gX = cxw - fh;
        float gY = cyw - (float)(wb + j);
        float r2 = gX * gX + gY * gY;      // exact small integers
        bool rpos = r2 > 0.0f;
        float R = rpos ? sqrtf(r2) : 0.0f;
        aR[j] = R;
        aT[j] = fast_atan2(gY, rpos ? gX : 1.0f);
        float invR = rpos ? (1.0f / R) : 0.0f;
        aS[j] = rpos ? gY * invR : 0.0f;   // sin(atan2(gY,gX)) == gY/R
        aC[j] = rpos ? gX * invR : 1.0f;   // cos(atan2(gY,gX)) == gX/R
        bool nearc = (fabsf(gX) < 3.0f) && (fabsf(gY) < 3.0f);
        aM[j] = (hv && nearc) ? 1.0f : 0.0f;
    }

    const size_t base = (size_t)b * NCH * HW + (size_t)(row * WW + wb);
    if (hv) {
        *(float4*)&out[base + 0 * (size_t)HW] = make_float4(aR[0], aR[1], aR[2], aR[3]);
        *(float4*)&out[base + 1 * (size_t)HW] = make_float4(aT[0], aT[1], aT[2], aT[3]);
        *(float4*)&out[base + 2 * (size_t)HW] = make_float4(aS[0], aS[1], aS[2], aS[3]);
        *(float4*)&out[base + 3 * (size_t)HW] = make_float4(aC[0], aC[1], aC[2], aC[3]);
    } else {
        *(float4*)&out[base + 0 * (size_t)HW] = *(const float4*)&gt[base + 0 * (size_t)HW];
        *(float4*)&out[base + 1 * (size_t)HW] = *(const float4*)&gt[base + 1 * (size_t)HW];
        *(float4*)&out[base + 2 * (size_t)HW] = *(const float4*)&gt[base + 2 * (size_t)HW];
        *(float4*)&out[base + 3 * (size_t)HW] = *(const float4*)&gt[base + 3 * (size_t)HW];
    }
    *(float4*)&out[base + 4 * (size_t)HW] = *(const float4*)&gt[base + 4 * (size_t)HW];
    *(float4*)&out[base + 5 * (size_t)HW] = make_float4(0.f, 0.f, 0.f, 0.f);
    *(float4*)&mask[(size_t)b * HW + (size_t)(row * WW + wb)] =
        make_float4(aM[0], aM[1], aM[2], aM[3]);
}

// ---------------------------------------------------------------------------
// Sparse blur over box(center, 12): mask patch staged in LDS, separable blur
// from LDS, box result stored to ws (blurbox) + per-batch atomicMax.
// Overlapping boxes compute bit-identical values -> benign races.
// ---------------------------------------------------------------------------
__device__ __forceinline__ void load_k1(const float* __restrict__ g2d, float* k1) {
    if (threadIdx.x < KSZ) {
        float s = 0.0f;
#pragma unroll
        for (int j = 0; j < KSZ; ++j) s += g2d[threadIdx.x * KSZ + j];
        k1[threadIdx.x] = s;
    }
}

__global__ __launch_bounds__(256) void k_blur_sparse(
    const float* __restrict__ centers,
    const float* __restrict__ mask,
    const float* __restrict__ g2d,
    float* __restrict__ blurbox,
    unsigned int* __restrict__ maxbuf)
{
    const int b  = blockIdx.y;
    const int ci = blockIdx.x;
    float cy = centers[(b * NCEN + ci) * 2 + 0];
    float cx = centers[(b * NCEN + ci) * 2 + 1];
    if (!((cy > 0.0f) || (cx > 0.0f))) return;     // uniform exit before barriers
    const int icx = (int)cx, icy = (int)cy;
    const int rA = max(icx - 12, 0), rB = min(icx + 12, HH - 1);
    const int cA = max(icy - 12, 0), cB = min(icy + 12, WW - 1);
    const int pr0 = max(rA - PADR, 0), pr1 = min(rB + PADR, HH - 1);
    const int pc0 = max(cA - PADR, 0), pc1 = min(cB + PADR, WW - 1);
    const int nr = pr1 - pr0 + 1, nc = pc1 - pc0 + 1;   // <= 45
    const int nh = rB - rA + 1,  nw = cB - cA + 1;      // <= 25

    __shared__ float k1[KSZ];
    __shared__ float patch[45 * 48];
    __shared__ float tmp[25 * 46];
    load_k1(g2d, k1);

    const float* mb = mask + (size_t)b * HW;
    for (int e = threadIdx.x; e < nr * nc; e += 256) {
        int r = e / nc, c = e - r * nc;
        patch[r * 48 + c] = mb[(pr0 + r) * WW + (pc0 + c)];
    }
    __syncthreads();

    for (int e = threadIdx.x; e < nh * nc; e += 256) {
        int lr = e / nc, j = e - lr * nc;
        int r  = rA + lr;
        float acc = 0.0f;
#pragma unroll
        for (int dv = -PADR; dv <= PADR; ++dv) {
            int q = refl(r + dv, HH);
            acc = fmaf(k1[dv + PADR], patch[(q - pr0) * 48 + j], acc);
        }
        tmp[lr * 46 + j] = acc;
    }
    __syncthreads();

    float vmax = 0.0f;
    float* bx = blurbox + (size_t)(b * NCEN + ci) * BOXSTRIDE;
    for (int e = threadIdx.x; e < nh * nw; e += 256) {
        int lr = e / nw, j = e - lr * nw;
        int w  = cA + j;
        float acc = 0.0f;
#pragma unroll
        for (int d = -PADR; d <= PADR; ++d) {
            int q = refl(w + d, WW);
            acc = fmaf(k1[d + PADR], tmp[lr * 46 + (q - pc0)], acc);
        }
        bx[lr * 25 + j] = acc;
        vmax = fmaxf(vmax, acc);
    }
#pragma unroll
    for (int off = 32; off > 0; off >>= 1)
        vmax = fmaxf(vmax, __shfl_down(vmax, off, 64));
    __shared__ float swr[4];
    const int lane = threadIdx.x & 63, wid = threadIdx.x >> 6;
    if (lane == 0) swr[wid] = vmax;
    __syncthreads();
    if (threadIdx.x == 0) {
        float m = fmaxf(fmaxf(swr[0], swr[1]), fmaxf(swr[2], swr[3]));
        atomicMax(&maxbuf[b], __float_as_uint(m));   // nonneg: uint order == float order
    }
}

__global__ __launch_bounds__(256) void k_norm_sparse(
    const float* __restrict__ centers,
    const float* __restrict__ blurbox,
    const unsigned int* __restrict__ maxbuf,
    float* __restrict__ out)
{
    const int b  = blockIdx.y;
    const int ci = blockIdx.x;
    float cy = centers[(b * NCEN + ci) * 2 + 0];
    float cx = centers[(b * NCEN + ci) * 2 + 1];
    if (!((cy > 0.0f) || (cx > 0.0f))) return;
    const int icx = (int)cx, icy = (int)cy;
    const int rA = max(icx - 12, 0), rB = min(icx + 12, HH - 1);
    const int cA = max(icy - 12, 0), cB = min(icy + 12, WW - 1);
    const int nh = rB - rA + 1, nw = cB - cA + 1;

    const float inv = 1.0f / fmaxf(__uint_as_float(maxbuf[b]), 1e-12f);
    const float* bx = blurbox + (size_t)(b * NCEN + ci) * BOXSTRIDE;
    float* o5 = out + ((size_t)b * NCH + 5) * HW;
    for (int e = threadIdx.x; e < nh * nw; e += 256) {
        int lr = e / nw, j = e - lr * nw;
        o5[(rA + lr) * WW + (cA + j)] = bx[lr * 25 + j] * inv;  // overwrites k_geom's zero
    }
}

} // namespace

extern "C" void kernel_launch(void* const* d_in, const int* in_sizes, int n_in,
                              void* d_out, int out_size, void* d_ws, size_t ws_size,
                              hipStream_t stream) {
    (void)in_sizes; (void)n_in; (void)out_size; (void)ws_size;
    const float* centers = (const float*)d_in[0];
    const float* gt      = (const float*)d_in[1];
    const float* g2d     = (const float*)d_in[2];
    float* out  = (float*)d_out;
    float* mask = (float*)d_ws;                                   // BB*HW floats
    float* blurbox = (float*)d_ws + (size_t)BB * HW;              // BB*NCEN*640 floats
    unsigned int* maxbuf =
        (unsigned int*)((float*)d_ws + (size_t)BB * HW + (size_t)BB * NCEN * BOXSTRIDE);

    dim3 gridG(256, BB);                       // 16x16 tiles of 32x32 px
    k_geom<<<gridG, 256, 0, stream>>>(centers, gt, out, mask, maxbuf);
    dim3 gridS(NCEN, BB);
    k_blur_sparse<<<gridS, 256, 0, stream>>>(centers, mask, g2d, blurbox, maxbuf);
    k_norm_sparse<<<gridS, 256, 0, stream>>>(centers, blurbox, maxbuf, out);
}

// Round 8
// 94.688 us; speedup vs baseline: 1.6995x; 1.0016x over previous
//
#include <hip/hip_runtime.h>
#include <math.h>
#include <limits.h>

namespace {
constexpr int BB   = 4;
constexpr int NCH  = 6;
constexpr int HH   = 512;
constexpr int WW   = 512;
constexpr int NCEN = 64;
constexpr int KSZ  = 21;
constexpr int PADR = 10;
constexpr int HW   = HH * WW;
constexpr int BOXSTRIDE = 640;       // per-(b,ci) blurbox slot (25*25 rounded up)

__device__ __forceinline__ int refl(int q, int n) {
    q = (q < 0) ? -q : q;
    q = (q >= n) ? (2 * n - 2 - q) : q;
    return q;
}

// ---------------------------------------------------------------------------
// Dense kernel, 32x32 tiles, 4 px/thread. Tile-pruned argmin:
//   ub = min_i maxdist2(c_i, tile);  keep i iff mindist2(c_i, tile) <= ub.
// Conservative proof: pruned i has d2(p) >= mindist2_i > ub >= d_win(p) for
// every tile pixel p (strict), so winners AND ties survive pruning.
// Packed key 64*d2 + i (exact ints < 2^31) keeps jnp.argmin tie-break.
// ISOLATION ROUND: theta via libm atan2f (fast_atan2 removed; only change).
// ---------------------------------------------------------------------------
__global__ __launch_bounds__(256) void k_geom(
    const float* __restrict__ centers,   // [B][NCEN][2] (cy, cx)
    const float* __restrict__ gt,        // [B][6][H][W]
    float* __restrict__ out,             // [B][6][H][W]
    float* __restrict__ mask,            // [B][H][W]
    unsigned int* __restrict__ maxbuf)   // [B]
{
    __shared__ float s_cxf[NCEN], s_cyf[NCEN];
    __shared__ int   s_kx[NCEN], s_ky8[NCEN], s_ki[NCEN];
    __shared__ int   s_cnt, s_hasv;

    const int b    = blockIdx.y;
    const int tid  = threadIdx.x;
    const int tIdx = blockIdx.x;          // 0..255
    const int r0   = (tIdx >> 4) * 32;    // tile row base (h)
    const int c0   = (tIdx & 15) * 32;    // tile col base (w)

    if (tIdx == 0 && tid == 0) maxbuf[b] = 0u;   // ws is 0xAA-poisoned

    if (tid < NCEN) {                     // wave 0 only: prune + compact
        float cy = centers[(b * NCEN + tid) * 2 + 0];
        float cx = centers[(b * NCEN + tid) * 2 + 1];
        bool valid = (cy > 0.0f) || (cx > 0.0f);
        s_cxf[tid] = cx;
        s_cyf[tid] = cy;
        // rows pair with cx, cols with cy (dx = h - cx, dy = w - cy)
        float r0f = (float)r0, r1f = (float)(r0 + 31);
        float c0f = (float)c0, c1f = (float)(c0 + 31);
        float drm = fmaxf(fmaxf(r0f - cx, cx - r1f), 0.0f);
        float dcm = fmaxf(fmaxf(c0f - cy, cy - c1f), 0.0f);
        float drM = fmaxf(cx - r0f, r1f - cx);
        float dcM = fmaxf(cy - c0f, c1f - cy);
        float mind2 = drm * drm + dcm * dcm;   // exact ints in f32
        float maxd2 = drM * drM + dcM * dcM;
        if (!valid) { mind2 = __int_as_float(0x7f800000); maxd2 = mind2; }
        float ub = maxd2;
#pragma unroll
        for (int off = 32; off > 0; off >>= 1)
            ub = fminf(ub, __shfl_xor(ub, off, 64));
        bool keep = valid && (mind2 <= ub);
        unsigned long long km = __ballot(keep);
        unsigned long long vm = __ballot(valid);
        if (keep) {
            int pos = __popcll(km & ((1ull << tid) - 1ull));
            s_kx[pos]  = (int)cx;
            s_ky8[pos] = ((int)cy) * 8;
            s_ki[pos]  = tid;              // ascending original index order
        }
        if (tid == 0) { s_cnt = (int)__popcll(km); s_hasv = (vm != 0ull) ? 1 : 0; }
    }
    __syncthreads();

    const int row = r0 + (tid >> 3);       // 32 rows, 8 threads/row
    const int wb  = c0 + (tid & 7) * 4;    // 4 consecutive pixels
    const int w8  = wb * 8;
    const int cnt = s_cnt;
    const bool hv = (s_hasv != 0);

    int b0 = INT_MAX, b1 = INT_MAX, b2 = INT_MAX, b3 = INT_MAX;
    for (int k = 0; k < cnt; ++k) {
        int dr   = row - s_kx[k];
        int base = (__mul24(dr, dr) << 6) + s_ki[k];   // 64*dr^2 + i
        int icy8 = s_ky8[k];
        int d0 = w8      - icy8; b0 = min(b0, __mul24(d0, d0) + base);
        int d1 = w8 + 8  - icy8; b1 = min(b1, __mul24(d1, d1) + base);
        int d2 = w8 + 16 - icy8; b2 = min(b2, __mul24(d2, d2) + base);
        int d3 = w8 + 24 - icy8; b3 = min(b3, __mul24(d3, d3) + base);
    }
    int bi[4] = { b0 & 63, b1 & 63, b2 & 63, b3 & 63 };

    float aR[4], aT[4], aS[4], aC[4], aM[4];
    const float fh = (float)row;
#pragma unroll
    for (int j = 0; j < 4; ++j) {
        float cxw = s_cxf[bi[j]];
        float cyw = s_cyf[bi[j]];
        float gX = cxw - fh;
        float gY = cyw - (float)(wb + j);
        float r2 = gX * gX + gY * gY;      // exact small integers
        bool rpos = r2 > 0.0f;
        float R = rpos ? sqrtf(r2) : 0.0f;
        aR[j] = R;
        aT[j] = atan2f(gY, rpos ? gX : 1.0f);
        float invR = rpos ? (1.0f / R) : 0.0f;
        aS[j] = rpos ? gY * invR : 0.0f;   // sin(atan2(gY,gX)) == gY/R
        aC[j] = rpos ? gX * invR : 1.0f;   // cos(atan2(gY,gX)) == gX/R
        bool nearc = (fabsf(gX) < 3.0f) && (fabsf(gY) < 3.0f);
        aM[j] = (hv && nearc) ? 1.0f : 0.0f;
    }

    const size_t base = (size_t)b * NCH * HW + (size_t)(row * WW + wb);
    if (hv) {
        *(float4*)&out[base + 0 * (size_t)HW] = make_float4(aR[0], aR[1], aR[2], aR[3]);
        *(float4*)&out[base + 1 * (size_t)HW] = make_float4(aT[0], aT[1], aT[2], aT[3]);
        *(float4*)&out[base + 2 * (size_t)HW] = make_float4(aS[0], aS[1], aS[2], aS[3]);
        *(float4*)&out[base + 3 * (size_t)HW] = make_float4(aC[0], aC[1], aC[2], aC[3]);
    } else {
        *(float4*)&out[base + 0 * (size_t)HW] = *(const float4*)&gt[base + 0 * (size_t)HW];
        *(float4*)&out[base + 1 * (size_t)HW] = *(const float4*)&gt[base + 1 * (size_t)HW];
        *(float4*)&out[base + 2 * (size_t)HW] = *(const float4*)&gt[base + 2 * (size_t)HW];
        *(float4*)&out[base + 3 * (size_t)HW] = *(const float4*)&gt[base + 3 * (size_t)HW];
    }
    *(float4*)&out[base + 4 * (size_t)HW] = *(const float4*)&gt[base + 4 * (size_t)HW];
    *(float4*)&out[base + 5 * (size_t)HW] = make_float4(0.f, 0.f, 0.f, 0.f);
    *(float4*)&mask[(size_t)b * HW + (size_t)(row * WW + wb)] =
        make_float4(aM[0], aM[1], aM[2], aM[3]);
}

// ---------------------------------------------------------------------------
// Sparse blur over box(center, 12): mask patch staged in LDS, separable blur
// from LDS, box result stored to ws (blurbox) + per-batch atomicMax.
// Overlapping boxes compute bit-identical values -> benign races.
// ---------------------------------------------------------------------------
__device__ __forceinline__ void load_k1(const float* __restrict__ g2d, float* k1) {
    if (threadIdx.x < KSZ) {
        float s = 0.0f;
#pragma unroll
        for (int j = 0; j < KSZ; ++j) s += g2d[threadIdx.x * KSZ + j];
        k1[threadIdx.x] = s;
    }
}

__global__ __launch_bounds__(256) void k_blur_sparse(
    const float* __restrict__ centers,
    const float* __restrict__ mask,
    const float* __restrict__ g2d,
    float* __restrict__ blurbox,
    unsigned int* __restrict__ maxbuf)
{
    const int b  = blockIdx.y;
    const int ci = blockIdx.x;
    float cy = centers[(b * NCEN + ci) * 2 + 0];
    float cx = centers[(b * NCEN + ci) * 2 + 1];
    if (!((cy > 0.0f) || (cx > 0.0f))) return;     // uniform exit before barriers
    const int icx = (int)cx, icy = (int)cy;
    const int rA = max(icx - 12, 0), rB = min(icx + 12, HH - 1);
    const int cA = max(icy - 12, 0), cB = min(icy + 12, WW - 1);
    const int pr0 = max(rA - PADR, 0), pr1 = min(rB + PADR, HH - 1);
    const int pc0 = max(cA - PADR, 0), pc1 = min(cB + PADR, WW - 1);
    const int nr = pr1 - pr0 + 1, nc = pc1 - pc0 + 1;   // <= 45
    const int nh = rB - rA + 1,  nw = cB - cA + 1;      // <= 25

    __shared__ float k1[KSZ];
    __shared__ float patch[45 * 48];
    __shared__ float tmp[25 * 46];
    load_k1(g2d, k1);

    const float* mb = mask + (size_t)b * HW;
    for (int e = threadIdx.x; e < nr * nc; e += 256) {
        int r = e / nc, c = e - r * nc;
        patch[r * 48 + c] = mb[(pr0 + r) * WW + (pc0 + c)];
    }
    __syncthreads();

    for (int e = threadIdx.x; e < nh * nc; e += 256) {
        int lr = e / nc, j = e - lr * nc;
        int r  = rA + lr;
        float acc = 0.0f;
#pragma unroll
        for (int dv = -PADR; dv <= PADR; ++dv) {
            int q = refl(r + dv, HH);
            acc = fmaf(k1[dv + PADR], patch[(q - pr0) * 48 + j], acc);
        }
        tmp[lr * 46 + j] = acc;
    }
    __syncthreads();

    float vmax = 0.0f;
    float* bx = blurbox + (size_t)(b * NCEN + ci) * BOXSTRIDE;
    for (int e = threadIdx.x; e < nh * nw; e += 256) {
        int lr = e / nw, j = e - lr * nw;
        int w  = cA + j;
        float acc = 0.0f;
#pragma unroll
        for (int d = -PADR; d <= PADR; ++d) {
            int q = refl(w + d, WW);
            acc = fmaf(k1[d + PADR], tmp[lr * 46 + (q - pc0)], acc);
        }
        bx[lr * 25 + j] = acc;
        vmax = fmaxf(vmax, acc);
    }
#pragma unroll
    for (int off = 32; off > 0; off >>= 1)
        vmax = fmaxf(vmax, __shfl_down(vmax, off, 64));
    __shared__ float swr[4];
    const int lane = threadIdx.x & 63, wid = threadIdx.x >> 6;
    if (lane == 0) swr[wid] = vmax;
    __syncthreads();
    if (threadIdx.x == 0) {
        float m = fmaxf(fmaxf(swr[0], swr[1]), fmaxf(swr[2], swr[3]));
        atomicMax(&maxbuf[b], __float_as_uint(m));   // nonneg: uint order == float order
    }
}

__global__ __launch_bounds__(256) void k_norm_sparse(
    const float* __restrict__ centers,
    const float* __restrict__ blurbox,
    const unsigned int* __restrict__ maxbuf,
    float* __restrict__ out)
{
    const int b  = blockIdx.y;
    const int ci = blockIdx.x;
    float cy = centers[(b * NCEN + ci) * 2 + 0];
    float cx = centers[(b * NCEN + ci) * 2 + 1];
    if (!((cy > 0.0f) || (cx > 0.0f))) return;
    const int icx = (int)cx, icy = (int)cy;
    const int rA = max(icx - 12, 0), rB = min(icx + 12, HH - 1);
    const int cA = max(icy - 12, 0), cB = min(icy + 12, WW - 1);
    const int nh = rB - rA + 1, nw = cB - cA + 1;

    const float inv = 1.0f / fmaxf(__uint_as_float(maxbuf[b]), 1e-12f);
    const float* bx = blurbox + (size_t)(b * NCEN + ci) * BOXSTRIDE;
    float* o5 = out + ((size_t)b * NCH + 5) * HW;
    for (int e = threadIdx.x; e < nh * nw; e += 256) {
        int lr = e / nw, j = e - lr * nw;
        o5[(rA + lr) * WW + (cA + j)] = bx[lr * 25 + j] * inv;  // overwrites k_geom's zero
    }
}

} // namespace

extern "C" void kernel_launch(void* const* d_in, const int* in_sizes, int n_in,
                              void* d_out, int out_size, void* d_ws, size_t ws_size,
                              hipStream_t stream) {
    (void)in_sizes; (void)n_in; (void)out_size; (void)ws_size;
    const float* centers = (const float*)d_in[0];
    const float* gt      = (const float*)d_in[1];
    const float* g2d     = (const float*)d_in[2];
    float* out  = (float*)d_out;
    float* mask = (float*)d_ws;                                   // BB*HW floats
    float* blurbox = (float*)d_ws + (size_t)BB * HW;              // BB*NCEN*640 floats
    unsigned int* maxbuf =
        (unsigned int*)((float*)d_ws + (size_t)BB * HW + (size_t)BB * NCEN * BOXSTRIDE);

    dim3 gridG(256, BB);                       // 16x16 tiles of 32x32 px
    k_geom<<<gridG, 256, 0, stream>>>(centers, gt, out, mask, maxbuf);
    dim3 gridS(NCEN, BB);
    k_blur_sparse<<<gridS, 256, 0, stream>>>(centers, mask, g2d, blurbox, maxbuf);
    k_norm_sparse<<<gridS, 256, 0, stream>>>(centers, blurbox, maxbuf, out);
}